// Round 1
// baseline (208.235 us; speedup 1.0000x reference)
//
#include <hip/hip_runtime.h>

#define NN 8192
#define NE 262144
#define DIN 512
#define DH 256
#define DZ 16

// ---------------- CSR build ----------------
__global__ void k_zero(int* __restrict__ p, int n) {
    int i = blockIdx.x * blockDim.x + threadIdx.x;
    if (i < n) p[i] = 0;
}

__global__ void k_hist(const int* __restrict__ row, int* __restrict__ cnt) {
    int e = blockIdx.x * blockDim.x + threadIdx.x;
    if (e < NE) atomicAdd(&cnt[row[e]], 1);
}

// single block, 1024 threads; each thread owns 8 consecutive bins
__global__ __launch_bounds__(1024) void k_scan(const int* __restrict__ cnt,
                                               int* __restrict__ row_ptr,
                                               int* __restrict__ cursor) {
    __shared__ int sdata[1024];
    int t = threadIdx.x;
    int local[8];
    int s = 0;
#pragma unroll
    for (int j = 0; j < 8; j++) { local[j] = cnt[t * 8 + j]; s += local[j]; }
    sdata[t] = s;
    __syncthreads();
    // inclusive Hillis-Steele scan over 1024 partials
    for (int off = 1; off < 1024; off <<= 1) {
        int v = (t >= off) ? sdata[t - off] : 0;
        __syncthreads();
        sdata[t] += v;
        __syncthreads();
    }
    int base = sdata[t] - s;  // exclusive prefix for this thread's first bin
#pragma unroll
    for (int j = 0; j < 8; j++) {
        row_ptr[t * 8 + j] = base;
        cursor[t * 8 + j]  = base;
        base += local[j];
    }
    if (t == 1023) row_ptr[NN] = base;  // == NE
}

__global__ void k_scatter(const int* __restrict__ row, const int* __restrict__ col,
                          const float* __restrict__ ew, int* __restrict__ cursor,
                          int* __restrict__ col_s, float* __restrict__ w_s) {
    int e = blockIdx.x * blockDim.x + threadIdx.x;
    if (e < NE) {
        int r = row[e];
        int pos = atomicAdd(&cursor[r], 1);
        col_s[pos] = col[e];
        w_s[pos]   = ew[e];
    }
}

// ---------------- GEMM1: support1[8192,256] = x[8192,512] @ w1[512,256] ----------------
// 64x64 tile, BK=16, 256 threads, per-thread 4x4, transposed-A LDS (pad 68)
__global__ __launch_bounds__(256) void k_gemm1(const float* __restrict__ X,
                                               const float* __restrict__ W,
                                               float* __restrict__ O) {
    __shared__ __align__(16) float aT[16 * 68];  // [k][m]
    __shared__ __align__(16) float bs[16 * 68];  // [k][n]
    int t = threadIdx.x;
    int m0 = blockIdx.x * 64;
    int n0 = blockIdx.y * 64;
    int tx = t & 15, ty = t >> 4;
    int lr = t >> 2;         // A row in tile, 0..63
    int lc = (t & 3) * 4;    // A k in tile, {0,4,8,12}
    int br = t >> 4;         // B k row, 0..15
    int bc = (t & 15) * 4;   // B col
    float acc[4][4] = {};
    for (int k0 = 0; k0 < DIN; k0 += 16) {
        __syncthreads();
        float4 av = *(const float4*)&X[(size_t)(m0 + lr) * DIN + k0 + lc];
        float4 bv = *(const float4*)&W[(size_t)(k0 + br) * DH + n0 + bc];
        aT[(lc + 0) * 68 + lr] = av.x;
        aT[(lc + 1) * 68 + lr] = av.y;
        aT[(lc + 2) * 68 + lr] = av.z;
        aT[(lc + 3) * 68 + lr] = av.w;
        *(float4*)&bs[br * 68 + bc] = bv;
        __syncthreads();
#pragma unroll
        for (int kk = 0; kk < 16; kk++) {
            float4 a4 = *(const float4*)&aT[kk * 68 + ty * 4];
            float4 b4 = *(const float4*)&bs[kk * 68 + tx * 4];
            float a[4] = {a4.x, a4.y, a4.z, a4.w};
            float b[4] = {b4.x, b4.y, b4.z, b4.w};
#pragma unroll
            for (int i = 0; i < 4; i++)
#pragma unroll
                for (int j = 0; j < 4; j++) acc[i][j] += a[i] * b[j];
        }
    }
#pragma unroll
    for (int i = 0; i < 4; i++) {
        float4 o = make_float4(acc[i][0], acc[i][1], acc[i][2], acc[i][3]);
        *(float4*)&O[(size_t)(m0 + ty * 4 + i) * DH + n0 + tx * 4] = o;
    }
}

// ---------------- SpMM1: h1 = relu(A @ support1), width 256, 1 block/row ----------------
__global__ __launch_bounds__(256) void k_spmm1(const float* __restrict__ S,
                                               const int* __restrict__ rp,
                                               const int* __restrict__ cs,
                                               const float* __restrict__ wsrt,
                                               float* __restrict__ H) {
    int r = blockIdx.x;
    int c = threadIdx.x;
    int e0 = rp[r], e1 = rp[r + 1];
    float acc0 = 0.f, acc1 = 0.f;
    int e = e0;
    for (; e + 1 < e1; e += 2) {
        int k0 = cs[e], k1 = cs[e + 1];
        float wa = wsrt[e], wb = wsrt[e + 1];
        acc0 += wa * S[(size_t)k0 * DH + c];
        acc1 += wb * S[(size_t)k1 * DH + c];
    }
    if (e < e1) acc0 += wsrt[e] * S[(size_t)cs[e] * DH + c];
    H[(size_t)r * DH + c] = fmaxf(acc0 + acc1, 0.f);
}

// ---------------- GEMM2: s2[8192,16] = h1[8192,256] @ w2[256,16] ----------------
__global__ __launch_bounds__(256) void k_gemm2(const float* __restrict__ H,
                                               const float* __restrict__ W2,
                                               float* __restrict__ S2) {
    __shared__ float w2s[DH * DZ];  // 16KB
    __shared__ float hs[16 * DH];   // 16KB
    int t = threadIdx.x;
    int r0 = blockIdx.x * 16;
    for (int j = t; j < DH * DZ; j += 256) w2s[j] = W2[j];
    for (int j = t; j < 16 * DH; j += 256) hs[j] = H[(size_t)r0 * DH + j];
    __syncthreads();
    int rl = t >> 4, c = t & 15;
    float acc = 0.f;
#pragma unroll 8
    for (int k = 0; k < DH; k++) acc += hs[rl * DH + k] * w2s[k * DZ + c];
    S2[(size_t)(r0 + rl) * DZ + c] = acc;
}

// ---------------- SpMM2: z = A @ s2, width 16, 16 rows/block ----------------
__global__ __launch_bounds__(256) void k_spmm2(const float* __restrict__ S2,
                                               const int* __restrict__ rp,
                                               const int* __restrict__ cs,
                                               const float* __restrict__ wsrt,
                                               float* __restrict__ Z) {
    int t = threadIdx.x;
    int rl = t >> 4, c = t & 15;
    int r = blockIdx.x * 16 + rl;
    int e0 = rp[r], e1 = rp[r + 1];
    float acc = 0.f;
    for (int e = e0; e < e1; ++e) acc += wsrt[e] * S2[(size_t)cs[e] * DZ + c];
    Z[(size_t)r * DZ + c] = acc;
}

// ---------------- GEMM3: adj[8192,8192] = z @ z.T, K=16 ----------------
// 64x64 tile per 256-thread block, transposed LDS (pad 68), per-thread 4x4
__global__ __launch_bounds__(256) void k_gemm3(const float* __restrict__ Z,
                                               float* __restrict__ O) {
    __shared__ __align__(16) float aT[16 * 68];  // [k][row]
    __shared__ __align__(16) float bT[16 * 68];  // [k][col]
    int t = threadIdx.x;
    int rb = blockIdx.y * 64;
    int cb = blockIdx.x * 64;
    int zr = t >> 2, zc = (t & 3) * 4;
    float4 av = *(const float4*)&Z[(size_t)(rb + zr) * DZ + zc];
    float4 bv = *(const float4*)&Z[(size_t)(cb + zr) * DZ + zc];
    aT[(zc + 0) * 68 + zr] = av.x;
    aT[(zc + 1) * 68 + zr] = av.y;
    aT[(zc + 2) * 68 + zr] = av.z;
    aT[(zc + 3) * 68 + zr] = av.w;
    bT[(zc + 0) * 68 + zr] = bv.x;
    bT[(zc + 1) * 68 + zr] = bv.y;
    bT[(zc + 2) * 68 + zr] = bv.z;
    bT[(zc + 3) * 68 + zr] = bv.w;
    __syncthreads();
    int tx = t & 15, ty = t >> 4;
    float acc[4][4] = {};
#pragma unroll
    for (int k = 0; k < 16; k++) {
        float4 a4 = *(const float4*)&aT[k * 68 + ty * 4];
        float4 b4 = *(const float4*)&bT[k * 68 + tx * 4];
        float a[4] = {a4.x, a4.y, a4.z, a4.w};
        float b[4] = {b4.x, b4.y, b4.z, b4.w};
#pragma unroll
        for (int i = 0; i < 4; i++)
#pragma unroll
            for (int j = 0; j < 4; j++) acc[i][j] += a[i] * b[j];
    }
#pragma unroll
    for (int i = 0; i < 4; i++) {
        float4 o = make_float4(acc[i][0], acc[i][1], acc[i][2], acc[i][3]);
        *(float4*)&O[(size_t)(rb + ty * 4 + i) * NN + cb + tx * 4] = o;
    }
}

extern "C" void kernel_launch(void* const* d_in, const int* in_sizes, int n_in,
                              void* d_out, int out_size, void* d_ws, size_t ws_size,
                              hipStream_t stream) {
    const float* x  = (const float*)d_in[0];  // [8192,512]
    const float* w1 = (const float*)d_in[1];  // [512,256]
    const float* w2 = (const float*)d_in[2];  // [256,16]
    const float* ew = (const float*)d_in[3];  // [E]
    const int*  row = (const int*)d_in[4];    // [E]
    const int*  col = (const int*)d_in[5];    // [E]
    float* out = (float*)d_out;               // [8192,8192]

    // small scratch in d_ws (~600KB needed)
    char* ws = (char*)d_ws;
    int*   row_ptr = (int*)ws;                  // 8193 ints
    int*   cursor  = (int*)(ws + 36864);        // 8192 ints
    float* z       = (float*)(ws + 73728);      // 8192*16 floats (512KB)

    // big intermediates live in d_out (overwritten last by gemm3, which only reads z)
    char* ob = (char*)d_out;
    float* support1 = (float*)ob;                          // 8MB
    float* h1       = (float*)(ob + 8u * 1024 * 1024);     // 8MB
    float* s2       = (float*)(ob + 16u * 1024 * 1024);    // 512KB
    int*   col_s    = (int*)(ob + 17u * 1024 * 1024);      // 1MB
    float* w_s      = (float*)(ob + 18u * 1024 * 1024);    // 1MB

    // CSR build
    k_zero<<<32, 256, 0, stream>>>(cursor, NN);
    k_hist<<<NE / 256, 256, 0, stream>>>(row, cursor);
    k_scan<<<1, 1024, 0, stream>>>(cursor, row_ptr, cursor);
    k_scatter<<<NE / 256, 256, 0, stream>>>(row, col, ew, cursor, col_s, w_s);

    // layer 1
    k_gemm1<<<dim3(NN / 64, DH / 64), 256, 0, stream>>>(x, w1, support1);
    k_spmm1<<<NN, 256, 0, stream>>>(support1, row_ptr, col_s, w_s, h1);

    // layer 2
    k_gemm2<<<NN / 16, 256, 0, stream>>>(h1, w2, s2);
    k_spmm2<<<NN / 16, 256, 0, stream>>>(s2, row_ptr, col_s, w_s, z);

    // decoder
    k_gemm3<<<dim3(NN / 64, NN / 64), 256, 0, stream>>>(z, out);
}

// Round 2
// 189.885 us; speedup vs baseline: 1.0966x; 1.0966x over previous
//
#include <hip/hip_runtime.h>

#define NN 8192
#define NE 262144
#define DIN 512
#define DH 256
#define DZ 16

typedef __attribute__((ext_vector_type(8))) short bf16x8;
typedef __attribute__((ext_vector_type(4))) float f32x4;

__device__ __forceinline__ ushort f2bf(float f) {
    uint u = __float_as_uint(f);
    uint r = (u + 0x7FFFu + ((u >> 16) & 1u)) >> 16;
    return (ushort)r;
}
__device__ __forceinline__ float bf2f(ushort h) {
    return __uint_as_float((uint)h << 16);
}

// ---------------- CSR build ----------------
__global__ void k_zero(int* __restrict__ p, int n) {
    int i = blockIdx.x * blockDim.x + threadIdx.x;
    if (i < n) p[i] = 0;
}

__global__ void k_hist(const int* __restrict__ row, int* __restrict__ cnt) {
    int e = blockIdx.x * blockDim.x + threadIdx.x;
    if (e < NE) atomicAdd(&cnt[row[e]], 1);
}

// single block, 1024 threads; each thread owns 8 consecutive bins
__global__ __launch_bounds__(1024) void k_scan(const int* __restrict__ cnt,
                                               int* __restrict__ row_ptr,
                                               int* __restrict__ cursor) {
    __shared__ int sdata[1024];
    int t = threadIdx.x;
    int local[8];
    int s = 0;
#pragma unroll
    for (int j = 0; j < 8; j++) { local[j] = cnt[t * 8 + j]; s += local[j]; }
    sdata[t] = s;
    __syncthreads();
    for (int off = 1; off < 1024; off <<= 1) {
        int v = (t >= off) ? sdata[t - off] : 0;
        __syncthreads();
        sdata[t] += v;
        __syncthreads();
    }
    int base = sdata[t] - s;
#pragma unroll
    for (int j = 0; j < 8; j++) {
        row_ptr[t * 8 + j] = base;
        cursor[t * 8 + j]  = base;
        base += local[j];
    }
    if (t == 1023) row_ptr[NN] = base;
}

__global__ void k_scatter(const int* __restrict__ row, const int* __restrict__ col,
                          const float* __restrict__ ew, int* __restrict__ cursor,
                          int* __restrict__ col_s, float* __restrict__ w_s) {
    int e = blockIdx.x * blockDim.x + threadIdx.x;
    if (e < NE) {
        int r = row[e];
        int pos = atomicAdd(&cursor[r], 1);
        col_s[pos] = col[e];
        w_s[pos]   = ew[e];
    }
}

// ---------------- split-bf16 conversions ----------------
// x [8192,512] f32 -> xhi,xlo [8192,512] bf16
__global__ void k_cvt_x(const float* __restrict__ X, ushort* __restrict__ Hi,
                        ushort* __restrict__ Lo) {
    int i = blockIdx.x * blockDim.x + threadIdx.x;  // over float4s
    float4 v = ((const float4*)X)[i];
    ushort4 h, l;
    h.x = f2bf(v.x); l.x = f2bf(v.x - bf2f(h.x));
    h.y = f2bf(v.y); l.y = f2bf(v.y - bf2f(h.y));
    h.z = f2bf(v.z); l.z = f2bf(v.z - bf2f(h.z));
    h.w = f2bf(v.w); l.w = f2bf(v.w - bf2f(h.w));
    ((ushort4*)Hi)[i] = h;
    ((ushort4*)Lo)[i] = l;
}

// w1 [512,256] f32 -> transposed w1t hi/lo [256,512] bf16
__global__ void k_cvt_w(const float* __restrict__ W, ushort* __restrict__ Hi,
                        ushort* __restrict__ Lo) {
    int o = blockIdx.x * blockDim.x + threadIdx.x;  // 256*512
    int n = o >> 9, k = o & 511;
    float f = W[(size_t)k * DH + n];
    ushort h = f2bf(f);
    Hi[o] = h;
    Lo[o] = f2bf(f - bf2f(h));
}

// ---------------- GEMM1 (MFMA, split-bf16): support1 = x @ w1 ----------------
// 64x64 tile, 4 waves (2x2), BK=64, A=[M][K] bf16, B=B^T=[N][K] bf16.
// 3 segments: hi*hi + hi*lo + lo*hi (lo*lo dropped, ~4e-6 rel).
__global__ __launch_bounds__(256) void k_gemm1_mfma(
    const ushort* __restrict__ Ahi, const ushort* __restrict__ Alo,
    const ushort* __restrict__ Bhi, const ushort* __restrict__ Blo,
    float* __restrict__ O) {
    __shared__ ushort As[64][72];  // pad 72: frag reads structural-min banks
    __shared__ ushort Bs[64][72];
    int t = threadIdx.x;
    int wave = t >> 6, lane = t & 63;
    int m0 = blockIdx.x * 64, n0 = blockIdx.y * 64;
    int wm = (wave >> 1) * 32, wn = (wave & 1) * 32;
    f32x4 acc[2][2] = {};
    // staging: vec8 id v -> row v>>3, col (v&7)*8 ; thread does v=t and v=t+256
    int r0 = t >> 3, c0 = (t & 7) * 8;
    int r1 = (t + 256) >> 3, c1 = c0;
    int fr = lane & 15, fg = lane >> 4;
#pragma unroll
    for (int seg = 0; seg < 3; ++seg) {
        const ushort* A = (seg == 2) ? Alo : Ahi;
        const ushort* B = (seg == 1) ? Blo : Bhi;
        for (int k0 = 0; k0 < DIN; k0 += 64) {
            __syncthreads();
            *(bf16x8*)&As[r0][c0] = *(const bf16x8*)&A[(size_t)(m0 + r0) * DIN + k0 + c0];
            *(bf16x8*)&As[r1][c1] = *(const bf16x8*)&A[(size_t)(m0 + r1) * DIN + k0 + c1];
            *(bf16x8*)&Bs[r0][c0] = *(const bf16x8*)&B[(size_t)(n0 + r0) * DIN + k0 + c0];
            *(bf16x8*)&Bs[r1][c1] = *(const bf16x8*)&B[(size_t)(n0 + r1) * DIN + k0 + c1];
            __syncthreads();
#pragma unroll
            for (int kk = 0; kk < 2; ++kk) {
                bf16x8 af[2], bb[2];
#pragma unroll
                for (int i = 0; i < 2; ++i)
                    af[i] = *(const bf16x8*)&As[wm + i * 16 + fr][kk * 32 + fg * 8];
#pragma unroll
                for (int j = 0; j < 2; ++j)
                    bb[j] = *(const bf16x8*)&Bs[wn + j * 16 + fr][kk * 32 + fg * 8];
#pragma unroll
                for (int i = 0; i < 2; ++i)
#pragma unroll
                    for (int j = 0; j < 2; ++j)
                        acc[i][j] = __builtin_amdgcn_mfma_f32_16x16x32_bf16(
                            af[i], bb[j], acc[i][j], 0, 0, 0);
            }
        }
    }
    // C/D: col = lane&15, row = (lane>>4)*4 + reg  [m89/m91]
#pragma unroll
    for (int i = 0; i < 2; ++i)
#pragma unroll
        for (int j = 0; j < 2; ++j)
#pragma unroll
            for (int r = 0; r < 4; ++r)
                O[(size_t)(m0 + wm + i * 16 + fg * 4 + r) * DH + n0 + wn + j * 16 + fr] =
                    acc[i][j][r];
}

// ---------------- SpMM1: h1 = relu(A @ support1), width 256, 1 block/row ----------------
__global__ __launch_bounds__(256) void k_spmm1(const float* __restrict__ S,
                                               const int* __restrict__ rp,
                                               const int* __restrict__ cs,
                                               const float* __restrict__ wsrt,
                                               float* __restrict__ H) {
    int r = blockIdx.x;
    int c = threadIdx.x;
    int e0 = rp[r], e1 = rp[r + 1];
    float a0 = 0.f, a1 = 0.f, a2 = 0.f, a3 = 0.f;
    int e = e0;
    for (; e + 3 < e1; e += 4) {
        int k0 = cs[e], k1 = cs[e + 1], k2 = cs[e + 2], k3 = cs[e + 3];
        float w0 = wsrt[e], w1 = wsrt[e + 1], w2 = wsrt[e + 2], w3 = wsrt[e + 3];
        a0 += w0 * S[(size_t)k0 * DH + c];
        a1 += w1 * S[(size_t)k1 * DH + c];
        a2 += w2 * S[(size_t)k2 * DH + c];
        a3 += w3 * S[(size_t)k3 * DH + c];
    }
    for (; e < e1; ++e) a0 += wsrt[e] * S[(size_t)cs[e] * DH + c];
    H[(size_t)r * DH + c] = fmaxf(a0 + a1 + a2 + a3, 0.f);
}

// ---------------- GEMM2: s2[8192,16] = h1[8192,256] @ w2[256,16] ----------------
__global__ __launch_bounds__(256) void k_gemm2(const float* __restrict__ H,
                                               const float* __restrict__ W2,
                                               float* __restrict__ S2) {
    __shared__ float w2s[DH * DZ];
    __shared__ float hs[16 * DH];
    int t = threadIdx.x;
    int r0 = blockIdx.x * 16;
    for (int j = t; j < DH * DZ; j += 256) w2s[j] = W2[j];
    for (int j = t; j < 16 * DH; j += 256) hs[j] = H[(size_t)r0 * DH + j];
    __syncthreads();
    int rl = t >> 4, c = t & 15;
    float acc = 0.f;
#pragma unroll 8
    for (int k = 0; k < DH; k++) acc += hs[rl * DH + k] * w2s[k * DZ + c];
    S2[(size_t)(r0 + rl) * DZ + c] = acc;
}

// ---------------- SpMM2: z = A @ s2, width 16, 16 rows/block ----------------
__global__ __launch_bounds__(256) void k_spmm2(const float* __restrict__ S2,
                                               const int* __restrict__ rp,
                                               const int* __restrict__ cs,
                                               const float* __restrict__ wsrt,
                                               float* __restrict__ Z) {
    int t = threadIdx.x;
    int rl = t >> 4, c = t & 15;
    int r = blockIdx.x * 16 + rl;
    int e0 = rp[r], e1 = rp[r + 1];
    float acc = 0.f;
    for (int e = e0; e < e1; ++e) acc += wsrt[e] * S2[(size_t)cs[e] * DZ + c];
    Z[(size_t)r * DZ + c] = acc;
}

// ---------------- GEMM3: adj[8192,8192] = z @ z.T, K=16 ----------------
__global__ __launch_bounds__(256) void k_gemm3(const float* __restrict__ Z,
                                               float* __restrict__ O) {
    __shared__ __align__(16) float aT[16 * 68];
    __shared__ __align__(16) float bT[16 * 68];
    int t = threadIdx.x;
    int rb = blockIdx.y * 64;
    int cb = blockIdx.x * 64;
    int zr = t >> 2, zc = (t & 3) * 4;
    float4 av = *(const float4*)&Z[(size_t)(rb + zr) * DZ + zc];
    float4 bv = *(const float4*)&Z[(size_t)(cb + zr) * DZ + zc];
    aT[(zc + 0) * 68 + zr] = av.x;
    aT[(zc + 1) * 68 + zr] = av.y;
    aT[(zc + 2) * 68 + zr] = av.z;
    aT[(zc + 3) * 68 + zr] = av.w;
    bT[(zc + 0) * 68 + zr] = bv.x;
    bT[(zc + 1) * 68 + zr] = bv.y;
    bT[(zc + 2) * 68 + zr] = bv.z;
    bT[(zc + 3) * 68 + zr] = bv.w;
    __syncthreads();
    int tx = t & 15, ty = t >> 4;
    float acc[4][4] = {};
#pragma unroll
    for (int k = 0; k < 16; k++) {
        float4 a4 = *(const float4*)&aT[k * 68 + ty * 4];
        float4 b4 = *(const float4*)&bT[k * 68 + tx * 4];
        float a[4] = {a4.x, a4.y, a4.z, a4.w};
        float b[4] = {b4.x, b4.y, b4.z, b4.w};
#pragma unroll
        for (int i = 0; i < 4; i++)
#pragma unroll
            for (int j = 0; j < 4; j++) acc[i][j] += a[i] * b[j];
    }
#pragma unroll
    for (int i = 0; i < 4; i++) {
        float4 o = make_float4(acc[i][0], acc[i][1], acc[i][2], acc[i][3]);
        *(float4*)&O[(size_t)(rb + ty * 4 + i) * NN + cb + tx * 4] = o;
    }
}

extern "C" void kernel_launch(void* const* d_in, const int* in_sizes, int n_in,
                              void* d_out, int out_size, void* d_ws, size_t ws_size,
                              hipStream_t stream) {
    const float* x  = (const float*)d_in[0];  // [8192,512]
    const float* w1 = (const float*)d_in[1];  // [512,256]
    const float* w2 = (const float*)d_in[2];  // [256,16]
    const float* ew = (const float*)d_in[3];  // [E]
    const int*  row = (const int*)d_in[4];    // [E]
    const int*  col = (const int*)d_in[5];    // [E]
    float* out = (float*)d_out;               // [8192,8192]

    // small scratch in d_ws (~600KB)
    char* ws = (char*)d_ws;
    int*   row_ptr = (int*)ws;                  // 8193 ints
    int*   cursor  = (int*)(ws + 36864);        // 8192 ints
    float* z       = (float*)(ws + 73728);      // 8192*16 floats

    // big intermediates live in d_out (gemm3 overwrites everything last, reads only z)
    char* ob = (char*)d_out;
    float*  support1 = (float*)ob;                          // 8MB @ 0
    float*  h1       = (float*)(ob + 8u * 1024 * 1024);     // 8MB
    float*  s2       = (float*)(ob + 16u * 1024 * 1024);    // 512KB
    int*    col_s    = (int*)(ob + 17u * 1024 * 1024);      // 1MB
    float*  w_s      = (float*)(ob + 18u * 1024 * 1024);    // 1MB
    ushort* xhi      = (ushort*)(ob + 20u * 1024 * 1024);   // 8MB
    ushort* xlo      = (ushort*)(ob + 28u * 1024 * 1024);   // 8MB
    ushort* w1thi    = (ushort*)(ob + 36u * 1024 * 1024);   // 256KB
    ushort* w1tlo    = (ushort*)(ob + 37u * 1024 * 1024);   // 256KB

    // CSR build
    k_zero<<<32, 256, 0, stream>>>(cursor, NN);
    k_hist<<<NE / 256, 256, 0, stream>>>(row, cursor);
    k_scan<<<1, 1024, 0, stream>>>(cursor, row_ptr, cursor);
    k_scatter<<<NE / 256, 256, 0, stream>>>(row, col, ew, cursor, col_s, w_s);

    // split-bf16 conversions
    k_cvt_x<<<(NN * DIN / 4) / 256, 256, 0, stream>>>(x, xhi, xlo);
    k_cvt_w<<<(DIN * DH) / 256, 256, 0, stream>>>(w1, w1thi, w1tlo);

    // layer 1
    k_gemm1_mfma<<<dim3(NN / 64, DH / 64), 256, 0, stream>>>(xhi, xlo, w1thi, w1tlo, support1);
    k_spmm1<<<NN, 256, 0, stream>>>(support1, row_ptr, col_s, w_s, h1);

    // layer 2
    k_gemm2<<<NN / 16, 256, 0, stream>>>(h1, w2, s2);
    k_spmm2<<<NN / 16, 256, 0, stream>>>(s2, row_ptr, col_s, w_s, z);

    // decoder
    k_gemm3<<<dim3(NN / 64, NN / 64), 256, 0, stream>>>(z, out);
}

// Round 3
// 164.437 us; speedup vs baseline: 1.2664x; 1.1548x over previous
//
#include <hip/hip_runtime.h>

#define NN 8192
#define NE 262144
#define DIN 512
#define DH 256
#define DZ 16

typedef __attribute__((ext_vector_type(8))) short bf16x8;
typedef __attribute__((ext_vector_type(4))) float f32x4;

__device__ __forceinline__ ushort f2bf(float f) {
    uint u = __float_as_uint(f);
    uint r = (u + 0x7FFFu + ((u >> 16) & 1u)) >> 16;
    return (ushort)r;
}
__device__ __forceinline__ float bf2f(ushort h) {
    return __uint_as_float((uint)h << 16);
}

// ---------------- fused prep: zero cursor + cvt x + cvt w1^T ----------------
// grid: [0,4096) x-float4s, [4096,4608) w elems, [4608,4640) cursor zero
__global__ void k_prep(const float* __restrict__ X, ushort* __restrict__ XHi,
                       ushort* __restrict__ XLo, const float* __restrict__ W,
                       ushort* __restrict__ WHi, ushort* __restrict__ WLo,
                       int* __restrict__ cursor) {
    int b = blockIdx.x;
    int t = threadIdx.x;
    if (b < 4096) {
        int i = b * 256 + t;
        float4 v = ((const float4*)X)[i];
        ushort4 h, l;
        h.x = f2bf(v.x); l.x = f2bf(v.x - bf2f(h.x));
        h.y = f2bf(v.y); l.y = f2bf(v.y - bf2f(h.y));
        h.z = f2bf(v.z); l.z = f2bf(v.z - bf2f(h.z));
        h.w = f2bf(v.w); l.w = f2bf(v.w - bf2f(h.w));
        ((ushort4*)XHi)[i] = h;
        ((ushort4*)XLo)[i] = l;
    } else if (b < 4608) {
        int o = (b - 4096) * 256 + t;  // 256*512 elems of w1t
        int n = o >> 9, k = o & 511;
        float f = W[(size_t)k * DH + n];
        ushort h = f2bf(f);
        WHi[o] = h;
        WLo[o] = f2bf(f - bf2f(h));
    } else {
        cursor[(b - 4608) * 256 + t] = 0;
    }
}

// ---------------- CSR build ----------------
__global__ void k_hist(const int* __restrict__ row, int* __restrict__ cnt) {
    int e = blockIdx.x * blockDim.x + threadIdx.x;
    if (e < NE) atomicAdd(&cnt[row[e]], 1);
}

__global__ __launch_bounds__(1024) void k_scan(const int* __restrict__ cnt,
                                               int* __restrict__ row_ptr,
                                               int* __restrict__ cursor) {
    __shared__ int sdata[1024];
    int t = threadIdx.x;
    int local[8];
    int s = 0;
#pragma unroll
    for (int j = 0; j < 8; j++) { local[j] = cnt[t * 8 + j]; s += local[j]; }
    sdata[t] = s;
    __syncthreads();
    for (int off = 1; off < 1024; off <<= 1) {
        int v = (t >= off) ? sdata[t - off] : 0;
        __syncthreads();
        sdata[t] += v;
        __syncthreads();
    }
    int base = sdata[t] - s;
#pragma unroll
    for (int j = 0; j < 8; j++) {
        row_ptr[t * 8 + j] = base;
        cursor[t * 8 + j]  = base;
        base += local[j];
    }
    if (t == 1023) row_ptr[NN] = base;
}

__global__ void k_scatter(const int* __restrict__ row, const int* __restrict__ col,
                          const float* __restrict__ ew, int* __restrict__ cursor,
                          int* __restrict__ col_s, float* __restrict__ w_s) {
    int e = blockIdx.x * blockDim.x + threadIdx.x;
    if (e < NE) {
        int r = row[e];
        int pos = atomicAdd(&cursor[r], 1);
        col_s[pos] = col[e];
        w_s[pos]   = ew[e];
    }
}

// ---------------- GEMM1 (MFMA, split-bf16): support1 = x @ w1 ----------------
__global__ __launch_bounds__(256) void k_gemm1_mfma(
    const ushort* __restrict__ Ahi, const ushort* __restrict__ Alo,
    const ushort* __restrict__ Bhi, const ushort* __restrict__ Blo,
    float* __restrict__ O) {
    __shared__ ushort As[64][72];
    __shared__ ushort Bs[64][72];
    int t = threadIdx.x;
    int wave = t >> 6, lane = t & 63;
    int m0 = blockIdx.x * 64, n0 = blockIdx.y * 64;
    int wm = (wave >> 1) * 32, wn = (wave & 1) * 32;
    f32x4 acc[2][2] = {};
    int r0 = t >> 3, c0 = (t & 7) * 8;
    int r1 = (t + 256) >> 3, c1 = c0;
    int fr = lane & 15, fg = lane >> 4;
#pragma unroll
    for (int seg = 0; seg < 3; ++seg) {
        const ushort* A = (seg == 2) ? Alo : Ahi;
        const ushort* B = (seg == 1) ? Blo : Bhi;
        for (int k0 = 0; k0 < DIN; k0 += 64) {
            __syncthreads();
            *(bf16x8*)&As[r0][c0] = *(const bf16x8*)&A[(size_t)(m0 + r0) * DIN + k0 + c0];
            *(bf16x8*)&As[r1][c1] = *(const bf16x8*)&A[(size_t)(m0 + r1) * DIN + k0 + c1];
            *(bf16x8*)&Bs[r0][c0] = *(const bf16x8*)&B[(size_t)(n0 + r0) * DIN + k0 + c0];
            *(bf16x8*)&Bs[r1][c1] = *(const bf16x8*)&B[(size_t)(n0 + r1) * DIN + k0 + c1];
            __syncthreads();
#pragma unroll
            for (int kk = 0; kk < 2; ++kk) {
                bf16x8 af[2], bb[2];
#pragma unroll
                for (int i = 0; i < 2; ++i)
                    af[i] = *(const bf16x8*)&As[wm + i * 16 + fr][kk * 32 + fg * 8];
#pragma unroll
                for (int j = 0; j < 2; ++j)
                    bb[j] = *(const bf16x8*)&Bs[wn + j * 16 + fr][kk * 32 + fg * 8];
#pragma unroll
                for (int i = 0; i < 2; ++i)
#pragma unroll
                    for (int j = 0; j < 2; ++j)
                        acc[i][j] = __builtin_amdgcn_mfma_f32_16x16x32_bf16(
                            af[i], bb[j], acc[i][j], 0, 0, 0);
            }
        }
    }
#pragma unroll
    for (int i = 0; i < 2; ++i)
#pragma unroll
        for (int j = 0; j < 2; ++j)
#pragma unroll
            for (int r = 0; r < 4; ++r)
                O[(size_t)(m0 + wm + i * 16 + fg * 4 + r) * DH + n0 + wn + j * 16 + fr] =
                    acc[i][j][r];
}

// ---------------- SpMM1: h1 = relu(A @ support1), width 256 ----------------
__global__ __launch_bounds__(256) void k_spmm1(const float* __restrict__ S,
                                               const int* __restrict__ rp,
                                               const int* __restrict__ cs,
                                               const float* __restrict__ wsrt,
                                               float* __restrict__ H) {
    int r = blockIdx.x;
    int c = threadIdx.x;
    int e0 = rp[r], e1 = rp[r + 1];
    float a0 = 0.f, a1 = 0.f, a2 = 0.f, a3 = 0.f;
    int e = e0;
    for (; e + 3 < e1; e += 4) {
        int k0 = cs[e], k1 = cs[e + 1], k2 = cs[e + 2], k3 = cs[e + 3];
        float w0 = wsrt[e], w1 = wsrt[e + 1], w2 = wsrt[e + 2], w3 = wsrt[e + 3];
        a0 += w0 * S[(size_t)k0 * DH + c];
        a1 += w1 * S[(size_t)k1 * DH + c];
        a2 += w2 * S[(size_t)k2 * DH + c];
        a3 += w3 * S[(size_t)k3 * DH + c];
    }
    for (; e < e1; ++e) a0 += wsrt[e] * S[(size_t)cs[e] * DH + c];
    H[(size_t)r * DH + c] = fmaxf(a0 + a1 + a2 + a3, 0.f);
}

// ---------------- GEMM2: s2 = h1 @ w2 ----------------
__global__ __launch_bounds__(256) void k_gemm2(const float* __restrict__ H,
                                               const float* __restrict__ W2,
                                               float* __restrict__ S2) {
    __shared__ float w2s[DH * DZ];
    __shared__ float hs[16 * DH];
    int t = threadIdx.x;
    int r0 = blockIdx.x * 16;
    for (int j = t; j < DH * DZ; j += 256) w2s[j] = W2[j];
    for (int j = t; j < 16 * DH; j += 256) hs[j] = H[(size_t)r0 * DH + j];
    __syncthreads();
    int rl = t >> 4, c = t & 15;
    float acc = 0.f;
#pragma unroll 8
    for (int k = 0; k < DH; k++) acc += hs[rl * DH + k] * w2s[k * DZ + c];
    S2[(size_t)(r0 + rl) * DZ + c] = acc;
}

// ---------------- SpMM2: z = A @ s2, epilogue -> split bf16 zhi/zlo ----------------
__global__ __launch_bounds__(256) void k_spmm2(const float* __restrict__ S2,
                                               const int* __restrict__ rp,
                                               const int* __restrict__ cs,
                                               const float* __restrict__ wsrt,
                                               ushort* __restrict__ ZHi,
                                               ushort* __restrict__ ZLo) {
    int t = threadIdx.x;
    int rl = t >> 4, c = t & 15;
    int r = blockIdx.x * 16 + rl;
    int e0 = rp[r], e1 = rp[r + 1];
    float acc = 0.f;
    for (int e = e0; e < e1; ++e) acc += wsrt[e] * S2[(size_t)cs[e] * DZ + c];
    ushort h = f2bf(acc);
    ZHi[(size_t)r * DZ + c] = h;
    ZLo[(size_t)r * DZ + c] = f2bf(acc - bf2f(h));
}

// ---------------- GEMM3 (MFMA split-bf16, K-packed): adj = z @ z.T ----------------
// 128x128 per 256-thr block, 4 waves 2x2, each wave 64x64 = 4x4 subtiles.
// Packed K=32: A=[chi|clo], B1=[rhi|rhi] -> chi*rhi + clo*rhi ; B2=[rlo|0] -> chi*rlo.
// Operand order mfma(colfrag, rowfrag): D's fr = adj-row, fg*4+reg = adj-col -> f32x4 stores.
__global__ __launch_bounds__(256) void k_gemm3_mfma(const ushort* __restrict__ ZHi,
                                                    const ushort* __restrict__ ZLo,
                                                    float* __restrict__ O) {
    int t = threadIdx.x;
    int wave = t >> 6, lane = t & 63;
    int rb = blockIdx.y * 128 + (wave >> 1) * 64;
    int cb = blockIdx.x * 128 + (wave & 1) * 64;
    int fr = lane & 15, fg = lane >> 4;
    int ko = (fg & 1) * 8;
    const ushort* asel = (fg < 2) ? ZHi : ZLo;  // packed [hi|lo] along K

    bf16x8 cpack[4], rhi[4], rlo[4];
    bf16x8 zero8 = {};
#pragma unroll
    for (int j = 0; j < 4; ++j)
        cpack[j] = *(const bf16x8*)&asel[(size_t)(cb + j * 16 + fr) * DZ + ko];
#pragma unroll
    for (int i = 0; i < 4; ++i) {
        rhi[i] = *(const bf16x8*)&ZHi[(size_t)(rb + i * 16 + fr) * DZ + ko];
        rlo[i] = (fg < 2) ? *(const bf16x8*)&ZLo[(size_t)(rb + i * 16 + fr) * DZ + ko]
                          : zero8;
    }
    f32x4 acc[4][4] = {};
#pragma unroll
    for (int i = 0; i < 4; ++i)
#pragma unroll
        for (int j = 0; j < 4; ++j) {
            acc[i][j] = __builtin_amdgcn_mfma_f32_16x16x32_bf16(cpack[j], rhi[i],
                                                                acc[i][j], 0, 0, 0);
            acc[i][j] = __builtin_amdgcn_mfma_f32_16x16x32_bf16(cpack[j], rlo[i],
                                                                acc[i][j], 0, 0, 0);
        }
#pragma unroll
    for (int i = 0; i < 4; ++i)
#pragma unroll
        for (int j = 0; j < 4; ++j)
            *(f32x4*)&O[(size_t)(rb + i * 16 + fr) * NN + cb + j * 16 + fg * 4] = acc[i][j];
}

extern "C" void kernel_launch(void* const* d_in, const int* in_sizes, int n_in,
                              void* d_out, int out_size, void* d_ws, size_t ws_size,
                              hipStream_t stream) {
    const float* x  = (const float*)d_in[0];
    const float* w1 = (const float*)d_in[1];
    const float* w2 = (const float*)d_in[2];
    const float* ew = (const float*)d_in[3];
    const int*  row = (const int*)d_in[4];
    const int*  col = (const int*)d_in[5];
    float* out = (float*)d_out;

    // small scratch in d_ws (~600KB)
    char* ws = (char*)d_ws;
    int*    row_ptr = (int*)ws;                    // 8193 ints
    int*    cursor  = (int*)(ws + 36864);          // 8192 ints
    ushort* zhi     = (ushort*)(ws + 73728);       // 256KB
    ushort* zlo     = (ushort*)(ws + 73728 + 262144);  // 256KB

    // big intermediates live in d_out (gemm3 overwrites everything last, reads only zhi/zlo)
    char* ob = (char*)d_out;
    float*  support1 = (float*)ob;                        // 8MB
    float*  h1       = (float*)(ob + 8u * 1024 * 1024);   // 8MB
    float*  s2       = (float*)(ob + 16u * 1024 * 1024);  // 512KB
    int*    col_s    = (int*)(ob + 17u * 1024 * 1024);    // 1MB
    float*  w_s      = (float*)(ob + 18u * 1024 * 1024);  // 1MB
    ushort* xhi      = (ushort*)(ob + 20u * 1024 * 1024); // 8MB
    ushort* xlo      = (ushort*)(ob + 28u * 1024 * 1024); // 8MB
    ushort* w1thi    = (ushort*)(ob + 36u * 1024 * 1024); // 256KB
    ushort* w1tlo    = (ushort*)(ob + 37u * 1024 * 1024); // 256KB

    // prep (cvt x, cvt w1^T, zero cursor) in one launch
    k_prep<<<4640, 256, 0, stream>>>(x, xhi, xlo, w1, w1thi, w1tlo, cursor);

    // CSR build
    k_hist<<<NE / 256, 256, 0, stream>>>(row, cursor);
    k_scan<<<1, 1024, 0, stream>>>(cursor, row_ptr, cursor);
    k_scatter<<<NE / 256, 256, 0, stream>>>(row, col, ew, cursor, col_s, w_s);

    // layer 1
    k_gemm1_mfma<<<dim3(NN / 64, DH / 64), 256, 0, stream>>>(xhi, xlo, w1thi, w1tlo, support1);
    k_spmm1<<<NN, 256, 0, stream>>>(support1, row_ptr, col_s, w_s, h1);

    // layer 2
    k_gemm2<<<NN / 16, 256, 0, stream>>>(h1, w2, s2);
    k_spmm2<<<NN / 16, 256, 0, stream>>>(s2, row_ptr, col_s, w_s, zhi, zlo);

    // decoder
    k_gemm3_mfma<<<dim3(NN / 128, NN / 128), 256, 0, stream>>>(zhi, zlo, out);
}

// Round 4
// 153.899 us; speedup vs baseline: 1.3531x; 1.0685x over previous
//
#include <hip/hip_runtime.h>

#define NN 8192
#define NE 262144
#define DIN 512
#define DH 256
#define DZ 16

typedef __attribute__((ext_vector_type(8))) short bf16x8;
typedef __attribute__((ext_vector_type(4))) float f32x4;

__device__ __forceinline__ ushort f2bf(float f) {
    uint u = __float_as_uint(f);
    uint r = (u + 0x7FFFu + ((u >> 16) & 1u)) >> 16;
    return (ushort)r;
}
__device__ __forceinline__ float bf2f(ushort h) {
    return __uint_as_float((uint)h << 16);
}

// ---------------- fused prep: zero cursor + cvt x + cvt w1^T ----------------
__global__ void k_prep(const float* __restrict__ X, ushort* __restrict__ XHi,
                       ushort* __restrict__ XLo, const float* __restrict__ W,
                       ushort* __restrict__ WHi, ushort* __restrict__ WLo,
                       int* __restrict__ cursor) {
    int b = blockIdx.x;
    int t = threadIdx.x;
    if (b < 4096) {
        int i = b * 256 + t;
        float4 v = ((const float4*)X)[i];
        ushort4 h, l;
        h.x = f2bf(v.x); l.x = f2bf(v.x - bf2f(h.x));
        h.y = f2bf(v.y); l.y = f2bf(v.y - bf2f(h.y));
        h.z = f2bf(v.z); l.z = f2bf(v.z - bf2f(h.z));
        h.w = f2bf(v.w); l.w = f2bf(v.w - bf2f(h.w));
        ((ushort4*)XHi)[i] = h;
        ((ushort4*)XLo)[i] = l;
    } else if (b < 4608) {
        int o = (b - 4096) * 256 + t;
        int n = o >> 9, k = o & 511;
        float f = W[(size_t)k * DH + n];
        ushort h = f2bf(f);
        WHi[o] = h;
        WLo[o] = f2bf(f - bf2f(h));
    } else {
        cursor[(b - 4608) * 256 + t] = 0;
    }
}

// ---------------- CSR build ----------------
__global__ void k_hist(const int* __restrict__ row, int* __restrict__ cnt) {
    int e = blockIdx.x * blockDim.x + threadIdx.x;
    if (e < NE) atomicAdd(&cnt[row[e]], 1);
}

__global__ __launch_bounds__(1024) void k_scan(const int* __restrict__ cnt,
                                               int* __restrict__ row_ptr,
                                               int* __restrict__ cursor) {
    __shared__ int sdata[1024];
    int t = threadIdx.x;
    int local[8];
    int s = 0;
#pragma unroll
    for (int j = 0; j < 8; j++) { local[j] = cnt[t * 8 + j]; s += local[j]; }
    sdata[t] = s;
    __syncthreads();
    for (int off = 1; off < 1024; off <<= 1) {
        int v = (t >= off) ? sdata[t - off] : 0;
        __syncthreads();
        sdata[t] += v;
        __syncthreads();
    }
    int base = sdata[t] - s;
#pragma unroll
    for (int j = 0; j < 8; j++) {
        row_ptr[t * 8 + j] = base;
        cursor[t * 8 + j]  = base;
        base += local[j];
    }
    if (t == 1023) row_ptr[NN] = base;
}

__global__ void k_scatter(const int* __restrict__ row, const int* __restrict__ col,
                          const float* __restrict__ ew, int* __restrict__ cursor,
                          int* __restrict__ col_s, float* __restrict__ w_s) {
    int e = blockIdx.x * blockDim.x + threadIdx.x;
    if (e < NE) {
        int r = row[e];
        int pos = atomicAdd(&cursor[r], 1);
        col_s[pos] = col[e];
        w_s[pos]   = ew[e];
    }
}

// ---------------- GEMM1 (MFMA, split-bf16): support1(bf16) = x @ w1 ----------------
__global__ __launch_bounds__(256) void k_gemm1_mfma(
    const ushort* __restrict__ Ahi, const ushort* __restrict__ Alo,
    const ushort* __restrict__ Bhi, const ushort* __restrict__ Blo,
    ushort* __restrict__ O) {
    __shared__ ushort As[64][72];
    __shared__ ushort Bs[64][72];
    int t = threadIdx.x;
    int wave = t >> 6, lane = t & 63;
    int m0 = blockIdx.x * 64, n0 = blockIdx.y * 64;
    int wm = (wave >> 1) * 32, wn = (wave & 1) * 32;
    f32x4 acc[2][2] = {};
    int r0 = t >> 3, c0 = (t & 7) * 8;
    int r1 = (t + 256) >> 3, c1 = c0;
    int fr = lane & 15, fg = lane >> 4;
#pragma unroll
    for (int seg = 0; seg < 3; ++seg) {
        const ushort* A = (seg == 2) ? Alo : Ahi;
        const ushort* B = (seg == 1) ? Blo : Bhi;
        for (int k0 = 0; k0 < DIN; k0 += 64) {
            __syncthreads();
            *(bf16x8*)&As[r0][c0] = *(const bf16x8*)&A[(size_t)(m0 + r0) * DIN + k0 + c0];
            *(bf16x8*)&As[r1][c1] = *(const bf16x8*)&A[(size_t)(m0 + r1) * DIN + k0 + c1];
            *(bf16x8*)&Bs[r0][c0] = *(const bf16x8*)&B[(size_t)(n0 + r0) * DIN + k0 + c0];
            *(bf16x8*)&Bs[r1][c1] = *(const bf16x8*)&B[(size_t)(n0 + r1) * DIN + k0 + c1];
            __syncthreads();
#pragma unroll
            for (int kk = 0; kk < 2; ++kk) {
                bf16x8 af[2], bb[2];
#pragma unroll
                for (int i = 0; i < 2; ++i)
                    af[i] = *(const bf16x8*)&As[wm + i * 16 + fr][kk * 32 + fg * 8];
#pragma unroll
                for (int j = 0; j < 2; ++j)
                    bb[j] = *(const bf16x8*)&Bs[wn + j * 16 + fr][kk * 32 + fg * 8];
#pragma unroll
                for (int i = 0; i < 2; ++i)
#pragma unroll
                    for (int j = 0; j < 2; ++j)
                        acc[i][j] = __builtin_amdgcn_mfma_f32_16x16x32_bf16(
                            af[i], bb[j], acc[i][j], 0, 0, 0);
            }
        }
    }
    // store bf16 (spmm1 gathers this; 4MB -> per-XCD L2 resident)
#pragma unroll
    for (int i = 0; i < 2; ++i)
#pragma unroll
        for (int j = 0; j < 2; ++j)
#pragma unroll
            for (int r = 0; r < 4; ++r)
                O[(size_t)(m0 + wm + i * 16 + fg * 4 + r) * DH + n0 + wn + j * 16 + fr] =
                    f2bf(acc[i][j][r]);
}

// ---------------- SpMM1: h1 = relu(A @ support1_bf16), 2 rows/block ----------------
// 128 threads per row; each thread owns a col-pair via one uint load (coalesced 256B/wave)
__global__ __launch_bounds__(256) void k_spmm1(const ushort* __restrict__ Sbf,
                                               const int* __restrict__ rp,
                                               const int* __restrict__ cs,
                                               const float* __restrict__ wsrt,
                                               float* __restrict__ H) {
    int t = threadIdx.x;
    int sub = t >> 7;      // row within pair
    int ht = t & 127;      // col-pair index
    int r = blockIdx.x * 2 + sub;
    int e0 = rp[r], e1 = rp[r + 1];
    float a0 = 0.f, a1 = 0.f, b0 = 0.f, b1 = 0.f;
    float c0 = 0.f, c1 = 0.f, d0 = 0.f, d1 = 0.f;
    int e = e0;
    for (; e + 3 < e1; e += 4) {
        int k0 = cs[e], k1 = cs[e + 1], k2 = cs[e + 2], k3 = cs[e + 3];
        float w0 = wsrt[e], w1 = wsrt[e + 1], w2 = wsrt[e + 2], w3 = wsrt[e + 3];
        uint p0 = *(const uint*)&Sbf[(size_t)k0 * DH + ht * 2];
        uint p1 = *(const uint*)&Sbf[(size_t)k1 * DH + ht * 2];
        uint p2 = *(const uint*)&Sbf[(size_t)k2 * DH + ht * 2];
        uint p3 = *(const uint*)&Sbf[(size_t)k3 * DH + ht * 2];
        a0 += w0 * bf2f((ushort)p0); a1 += w0 * bf2f((ushort)(p0 >> 16));
        b0 += w1 * bf2f((ushort)p1); b1 += w1 * bf2f((ushort)(p1 >> 16));
        c0 += w2 * bf2f((ushort)p2); c1 += w2 * bf2f((ushort)(p2 >> 16));
        d0 += w3 * bf2f((ushort)p3); d1 += w3 * bf2f((ushort)(p3 >> 16));
    }
    for (; e < e1; ++e) {
        float w0 = wsrt[e];
        uint p0 = *(const uint*)&Sbf[(size_t)cs[e] * DH + ht * 2];
        a0 += w0 * bf2f((ushort)p0); a1 += w0 * bf2f((ushort)(p0 >> 16));
    }
    float2 o;
    o.x = fmaxf(a0 + b0 + c0 + d0, 0.f);
    o.y = fmaxf(a1 + b1 + c1 + d1, 0.f);
    *(float2*)&H[(size_t)r * DH + ht * 2] = o;
}

// ---------------- GEMM2: s2 = h1 @ w2 ----------------
__global__ __launch_bounds__(256) void k_gemm2(const float* __restrict__ H,
                                               const float* __restrict__ W2,
                                               float* __restrict__ S2) {
    __shared__ float w2s[DH * DZ];
    __shared__ float hs[16 * DH];
    int t = threadIdx.x;
    int r0 = blockIdx.x * 16;
    for (int j = t; j < DH * DZ; j += 256) w2s[j] = W2[j];
    for (int j = t; j < 16 * DH; j += 256) hs[j] = H[(size_t)r0 * DH + j];
    __syncthreads();
    int rl = t >> 4, c = t & 15;
    float acc = 0.f;
#pragma unroll 8
    for (int k = 0; k < DH; k++) acc += hs[rl * DH + k] * w2s[k * DZ + c];
    S2[(size_t)(r0 + rl) * DZ + c] = acc;
}

// ---------------- SpMM2: z = A @ s2, epilogue -> split bf16 zhi/zlo ----------------
__global__ __launch_bounds__(256) void k_spmm2(const float* __restrict__ S2,
                                               const int* __restrict__ rp,
                                               const int* __restrict__ cs,
                                               const float* __restrict__ wsrt,
                                               ushort* __restrict__ ZHi,
                                               ushort* __restrict__ ZLo) {
    int t = threadIdx.x;
    int rl = t >> 4, c = t & 15;
    int r = blockIdx.x * 16 + rl;
    int e0 = rp[r], e1 = rp[r + 1];
    float acc = 0.f;
    for (int e = e0; e < e1; ++e) acc += wsrt[e] * S2[(size_t)cs[e] * DZ + c];
    ushort h = f2bf(acc);
    ZHi[(size_t)r * DZ + c] = h;
    ZLo[(size_t)r * DZ + c] = f2bf(acc - bf2f(h));
}

// ---------------- GEMM3 (MFMA split-bf16, K-packed): adj = z @ z.T ----------------
__global__ __launch_bounds__(256) void k_gemm3_mfma(const ushort* __restrict__ ZHi,
                                                    const ushort* __restrict__ ZLo,
                                                    float* __restrict__ O) {
    int t = threadIdx.x;
    int wave = t >> 6, lane = t & 63;
    int rb = blockIdx.y * 128 + (wave >> 1) * 64;
    int cb = blockIdx.x * 128 + (wave & 1) * 64;
    int fr = lane & 15, fg = lane >> 4;
    int ko = (fg & 1) * 8;
    const ushort* asel = (fg < 2) ? ZHi : ZLo;

    bf16x8 cpack[4], rhi[4], rlo[4];
    bf16x8 zero8 = {};
#pragma unroll
    for (int j = 0; j < 4; ++j)
        cpack[j] = *(const bf16x8*)&asel[(size_t)(cb + j * 16 + fr) * DZ + ko];
#pragma unroll
    for (int i = 0; i < 4; ++i) {
        rhi[i] = *(const bf16x8*)&ZHi[(size_t)(rb + i * 16 + fr) * DZ + ko];
        rlo[i] = (fg < 2) ? *(const bf16x8*)&ZLo[(size_t)(rb + i * 16 + fr) * DZ + ko]
                          : zero8;
    }
    f32x4 acc[4][4] = {};
#pragma unroll
    for (int i = 0; i < 4; ++i)
#pragma unroll
        for (int j = 0; j < 4; ++j) {
            acc[i][j] = __builtin_amdgcn_mfma_f32_16x16x32_bf16(cpack[j], rhi[i],
                                                                acc[i][j], 0, 0, 0);
            acc[i][j] = __builtin_amdgcn_mfma_f32_16x16x32_bf16(cpack[j], rlo[i],
                                                                acc[i][j], 0, 0, 0);
        }
#pragma unroll
    for (int i = 0; i < 4; ++i)
#pragma unroll
        for (int j = 0; j < 4; ++j)
            *(f32x4*)&O[(size_t)(rb + i * 16 + fr) * NN + cb + j * 16 + fg * 4] = acc[i][j];
}

extern "C" void kernel_launch(void* const* d_in, const int* in_sizes, int n_in,
                              void* d_out, int out_size, void* d_ws, size_t ws_size,
                              hipStream_t stream) {
    const float* x  = (const float*)d_in[0];
    const float* w1 = (const float*)d_in[1];
    const float* w2 = (const float*)d_in[2];
    const float* ew = (const float*)d_in[3];
    const int*  row = (const int*)d_in[4];
    const int*  col = (const int*)d_in[5];
    float* out = (float*)d_out;

    char* ws = (char*)d_ws;
    int*    row_ptr = (int*)ws;
    int*    cursor  = (int*)(ws + 36864);
    ushort* zhi     = (ushort*)(ws + 73728);
    ushort* zlo     = (ushort*)(ws + 73728 + 262144);

    char* ob = (char*)d_out;
    ushort* support1 = (ushort*)ob;                       // 4MB bf16
    float*  h1       = (float*)(ob + 8u * 1024 * 1024);   // 8MB
    float*  s2       = (float*)(ob + 16u * 1024 * 1024);  // 512KB
    int*    col_s    = (int*)(ob + 17u * 1024 * 1024);    // 1MB
    float*  w_s      = (float*)(ob + 18u * 1024 * 1024);  // 1MB
    ushort* xhi      = (ushort*)(ob + 20u * 1024 * 1024); // 8MB
    ushort* xlo      = (ushort*)(ob + 28u * 1024 * 1024); // 8MB
    ushort* w1thi    = (ushort*)(ob + 36u * 1024 * 1024); // 256KB
    ushort* w1tlo    = (ushort*)(ob + 37u * 1024 * 1024); // 256KB

    k_prep<<<4640, 256, 0, stream>>>(x, xhi, xlo, w1, w1thi, w1tlo, cursor);

    k_hist<<<NE / 256, 256, 0, stream>>>(row, cursor);
    k_scan<<<1, 1024, 0, stream>>>(cursor, row_ptr, cursor);
    k_scatter<<<NE / 256, 256, 0, stream>>>(row, col, ew, cursor, col_s, w_s);

    k_gemm1_mfma<<<dim3(NN / 64, DH / 64), 256, 0, stream>>>(xhi, xlo, w1thi, w1tlo, support1);
    k_spmm1<<<NN / 2, 256, 0, stream>>>(support1, row_ptr, col_s, w_s, h1);

    k_gemm2<<<NN / 16, 256, 0, stream>>>(h1, w2, s2);
    k_spmm2<<<NN / 16, 256, 0, stream>>>(s2, row_ptr, col_s, w_s, zhi, zlo);

    k_gemm3_mfma<<<dim3(NN / 128, NN / 128), 256, 0, stream>>>(zhi, zlo, out);
}

// Round 5
// 145.196 us; speedup vs baseline: 1.4342x; 1.0599x over previous
//
#include <hip/hip_runtime.h>

#define NN 8192
#define NE 262144
#define DIN 512
#define DH 256
#define DZ 16

typedef __attribute__((ext_vector_type(8))) short bf16x8;
typedef __attribute__((ext_vector_type(4))) float f32x4;

__device__ __forceinline__ ushort f2bf(float f) {
    uint u = __float_as_uint(f);
    uint r = (u + 0x7FFFu + ((u >> 16) & 1u)) >> 16;
    return (ushort)r;
}
__device__ __forceinline__ float bf2f(ushort h) {
    return __uint_as_float((uint)h << 16);
}

// ---------------- fused prep: cvt x (hi) + cvt w1^T (hi) + zero cursor ----------------
__global__ void k_prep(const float* __restrict__ X, ushort* __restrict__ XBf,
                       const float* __restrict__ W, ushort* __restrict__ WBf,
                       int* __restrict__ cursor) {
    int b = blockIdx.x;
    int t = threadIdx.x;
    if (b < 4096) {
        int i = b * 256 + t;
        float4 v = ((const float4*)X)[i];
        ushort4 h;
        h.x = f2bf(v.x);
        h.y = f2bf(v.y);
        h.z = f2bf(v.z);
        h.w = f2bf(v.w);
        ((ushort4*)XBf)[i] = h;
    } else if (b < 4608) {
        int o = (b - 4096) * 256 + t;  // 256*512 elems of w1t
        int n = o >> 9, k = o & 511;
        WBf[o] = f2bf(W[(size_t)k * DH + n]);
    } else {
        cursor[(b - 4608) * 256 + t] = 0;
    }
}

// ---------------- CSR build ----------------
__global__ void k_hist(const int* __restrict__ row, int* __restrict__ cnt) {
    int e = blockIdx.x * blockDim.x + threadIdx.x;
    if (e < NE) atomicAdd(&cnt[row[e]], 1);
}

// 1024 threads, 8 bins each; wave shfl scan + 16 wave-sums -> 2 barriers total
__global__ __launch_bounds__(1024) void k_scan(const int* __restrict__ cnt,
                                               int* __restrict__ row_ptr,
                                               int* __restrict__ cursor) {
    __shared__ int wsum[16];
    int t = threadIdx.x;
    int wave = t >> 6, lane = t & 63;
    int4 v0 = *(const int4*)&cnt[t * 8];
    int4 v1 = *(const int4*)&cnt[t * 8 + 4];
    int local[8] = {v0.x, v0.y, v0.z, v0.w, v1.x, v1.y, v1.z, v1.w};
    int s = 0;
#pragma unroll
    for (int j = 0; j < 8; j++) s += local[j];
    // inclusive wave scan of s
    int si = s;
#pragma unroll
    for (int off = 1; off < 64; off <<= 1) {
        int u = __shfl_up(si, off);
        if (lane >= off) si += u;
    }
    if (lane == 63) wsum[wave] = si;
    __syncthreads();
    if (t < 16) {
        int w = wsum[t];
#pragma unroll
        for (int off = 1; off < 16; off <<= 1) {
            int u = __shfl_up(w, off);
            if (t >= off) w += u;
        }
        wsum[t] = w;
    }
    __syncthreads();
    int base = (wave ? wsum[wave - 1] : 0) + si - s;  // exclusive prefix of first bin
#pragma unroll
    for (int j = 0; j < 8; j++) {
        row_ptr[t * 8 + j] = base;
        cursor[t * 8 + j]  = base;
        base += local[j];
    }
    if (t == 1023) row_ptr[NN] = base;
}

__global__ void k_scatter(const int* __restrict__ row, const int* __restrict__ col,
                          const float* __restrict__ ew, int* __restrict__ cursor,
                          int* __restrict__ col_s, float* __restrict__ w_s) {
    int e = blockIdx.x * blockDim.x + threadIdx.x;
    if (e < NE) {
        int r = row[e];
        int pos = atomicAdd(&cursor[r], 1);
        col_s[pos] = col[e];
        w_s[pos]   = ew[e];
    }
}

// ---------------- GEMM1 (MFMA bf16): support1(bf16) = x @ w1 ----------------
__global__ __launch_bounds__(256) void k_gemm1_mfma(const ushort* __restrict__ A,
                                                    const ushort* __restrict__ B,
                                                    ushort* __restrict__ O) {
    __shared__ ushort As[64][72];
    __shared__ ushort Bs[64][72];
    int t = threadIdx.x;
    int wave = t >> 6, lane = t & 63;
    int m0 = blockIdx.x * 64, n0 = blockIdx.y * 64;
    int wm = (wave >> 1) * 32, wn = (wave & 1) * 32;
    f32x4 acc[2][2] = {};
    int r0 = t >> 3, c0 = (t & 7) * 8;
    int r1 = r0 + 32;
    int fr = lane & 15, fg = lane >> 4;
    for (int k0 = 0; k0 < DIN; k0 += 64) {
        __syncthreads();
        *(bf16x8*)&As[r0][c0] = *(const bf16x8*)&A[(size_t)(m0 + r0) * DIN + k0 + c0];
        *(bf16x8*)&As[r1][c0] = *(const bf16x8*)&A[(size_t)(m0 + r1) * DIN + k0 + c0];
        *(bf16x8*)&Bs[r0][c0] = *(const bf16x8*)&B[(size_t)(n0 + r0) * DIN + k0 + c0];
        *(bf16x8*)&Bs[r1][c0] = *(const bf16x8*)&B[(size_t)(n0 + r1) * DIN + k0 + c0];
        __syncthreads();
#pragma unroll
        for (int kk = 0; kk < 2; ++kk) {
            bf16x8 af[2], bb[2];
#pragma unroll
            for (int i = 0; i < 2; ++i)
                af[i] = *(const bf16x8*)&As[wm + i * 16 + fr][kk * 32 + fg * 8];
#pragma unroll
            for (int j = 0; j < 2; ++j)
                bb[j] = *(const bf16x8*)&Bs[wn + j * 16 + fr][kk * 32 + fg * 8];
#pragma unroll
            for (int i = 0; i < 2; ++i)
#pragma unroll
                for (int j = 0; j < 2; ++j)
                    acc[i][j] = __builtin_amdgcn_mfma_f32_16x16x32_bf16(
                        af[i], bb[j], acc[i][j], 0, 0, 0);
        }
    }
#pragma unroll
    for (int i = 0; i < 2; ++i)
#pragma unroll
        for (int j = 0; j < 2; ++j)
#pragma unroll
            for (int r = 0; r < 4; ++r)
                O[(size_t)(m0 + wm + i * 16 + fg * 4 + r) * DH + n0 + wn + j * 16 + fr] =
                    f2bf(acc[i][j][r]);
}

// ---------------- fused SpMM1+GEMM2: s2 = (relu(A @ support1)) @ w2 ----------------
// 2 rows/block; phase1: gather h rows (reg) -> LDS; phase2: s2 via 8-lane dot+shfl reduce
__global__ __launch_bounds__(256) void k_spmm1_gemm2(const ushort* __restrict__ Sbf,
                                                     const int* __restrict__ rp,
                                                     const int* __restrict__ cs,
                                                     const float* __restrict__ wsrt,
                                                     const float* __restrict__ W2,
                                                     float* __restrict__ S2) {
    __shared__ float w2s[DH * DZ];  // 16KB, [k][j]
    __shared__ float hs[2][DH];     // 2KB
    int t = threadIdx.x;
    // stage w2 (independent of phase 1)
#pragma unroll
    for (int i = t; i < DH * DZ / 4; i += 256)
        ((float4*)w2s)[i] = ((const float4*)W2)[i];
    int sub = t >> 7;
    int ht = t & 127;
    int r = blockIdx.x * 2 + sub;
    int e0 = rp[r], e1 = rp[r + 1];
    float a0 = 0.f, a1 = 0.f, b0 = 0.f, b1 = 0.f;
    float c0 = 0.f, c1 = 0.f, d0 = 0.f, d1 = 0.f;
    int e = e0;
    for (; e + 3 < e1; e += 4) {
        int k0 = cs[e], k1 = cs[e + 1], k2 = cs[e + 2], k3 = cs[e + 3];
        float w0 = wsrt[e], w1 = wsrt[e + 1], w2_ = wsrt[e + 2], w3 = wsrt[e + 3];
        uint p0 = *(const uint*)&Sbf[(size_t)k0 * DH + ht * 2];
        uint p1 = *(const uint*)&Sbf[(size_t)k1 * DH + ht * 2];
        uint p2 = *(const uint*)&Sbf[(size_t)k2 * DH + ht * 2];
        uint p3 = *(const uint*)&Sbf[(size_t)k3 * DH + ht * 2];
        a0 += w0 * bf2f((ushort)p0); a1 += w0 * bf2f((ushort)(p0 >> 16));
        b0 += w1 * bf2f((ushort)p1); b1 += w1 * bf2f((ushort)(p1 >> 16));
        c0 += w2_ * bf2f((ushort)p2); c1 += w2_ * bf2f((ushort)(p2 >> 16));
        d0 += w3 * bf2f((ushort)p3); d1 += w3 * bf2f((ushort)(p3 >> 16));
    }
    for (; e < e1; ++e) {
        float w0 = wsrt[e];
        uint p0 = *(const uint*)&Sbf[(size_t)cs[e] * DH + ht * 2];
        a0 += w0 * bf2f((ushort)p0); a1 += w0 * bf2f((ushort)(p0 >> 16));
    }
    float2 o;
    o.x = fmaxf(a0 + b0 + c0 + d0, 0.f);
    o.y = fmaxf(a1 + b1 + c1 + d1, 0.f);
    *(float2*)&hs[sub][ht * 2] = o;
    __syncthreads();
    // phase 2: t = sub*128 + j*8 + g ; 8 threads per output, 32 k each
    int j = (t >> 3) & 15, g = t & 7;
    float acc = 0.f;
#pragma unroll
    for (int kk = 0; kk < 32; ++kk) {
        int k = g * 32 + kk;
        acc += hs[sub][k] * w2s[k * DZ + j];
    }
    acc += __shfl_xor(acc, 1);
    acc += __shfl_xor(acc, 2);
    acc += __shfl_xor(acc, 4);
    if (g == 0) S2[(size_t)r * DZ + j] = acc;
}

// ---------------- SpMM2: z = A @ s2, epilogue -> split bf16 zhi/zlo ----------------
__global__ __launch_bounds__(256) void k_spmm2(const float* __restrict__ S2,
                                               const int* __restrict__ rp,
                                               const int* __restrict__ cs,
                                               const float* __restrict__ wsrt,
                                               ushort* __restrict__ ZHi,
                                               ushort* __restrict__ ZLo) {
    int t = threadIdx.x;
    int rl = t >> 4, c = t & 15;
    int r = blockIdx.x * 16 + rl;
    int e0 = rp[r], e1 = rp[r + 1];
    float acc = 0.f;
    for (int e = e0; e < e1; ++e) acc += wsrt[e] * S2[(size_t)cs[e] * DZ + c];
    ushort h = f2bf(acc);
    ZHi[(size_t)r * DZ + c] = h;
    ZLo[(size_t)r * DZ + c] = f2bf(acc - bf2f(h));
}

// ---------------- GEMM3 (MFMA split-bf16, K-packed): adj = z @ z.T ----------------
__global__ __launch_bounds__(256) void k_gemm3_mfma(const ushort* __restrict__ ZHi,
                                                    const ushort* __restrict__ ZLo,
                                                    float* __restrict__ O) {
    int t = threadIdx.x;
    int wave = t >> 6, lane = t & 63;
    int rb = blockIdx.y * 128 + (wave >> 1) * 64;
    int cb = blockIdx.x * 128 + (wave & 1) * 64;
    int fr = lane & 15, fg = lane >> 4;
    int ko = (fg & 1) * 8;
    const ushort* asel = (fg < 2) ? ZHi : ZLo;

    bf16x8 cpack[4], rhi[4], rlo[4];
    bf16x8 zero8 = {};
#pragma unroll
    for (int j = 0; j < 4; ++j)
        cpack[j] = *(const bf16x8*)&asel[(size_t)(cb + j * 16 + fr) * DZ + ko];
#pragma unroll
    for (int i = 0; i < 4; ++i) {
        rhi[i] = *(const bf16x8*)&ZHi[(size_t)(rb + i * 16 + fr) * DZ + ko];
        rlo[i] = (fg < 2) ? *(const bf16x8*)&ZLo[(size_t)(rb + i * 16 + fr) * DZ + ko]
                          : zero8;
    }
    f32x4 acc[4][4] = {};
#pragma unroll
    for (int i = 0; i < 4; ++i)
#pragma unroll
        for (int j = 0; j < 4; ++j) {
            acc[i][j] = __builtin_amdgcn_mfma_f32_16x16x32_bf16(cpack[j], rhi[i],
                                                                acc[i][j], 0, 0, 0);
            acc[i][j] = __builtin_amdgcn_mfma_f32_16x16x32_bf16(cpack[j], rlo[i],
                                                                acc[i][j], 0, 0, 0);
        }
#pragma unroll
    for (int i = 0; i < 4; ++i)
#pragma unroll
        for (int j = 0; j < 4; ++j)
            *(f32x4*)&O[(size_t)(rb + i * 16 + fr) * NN + cb + j * 16 + fg * 4] = acc[i][j];
}

extern "C" void kernel_launch(void* const* d_in, const int* in_sizes, int n_in,
                              void* d_out, int out_size, void* d_ws, size_t ws_size,
                              hipStream_t stream) {
    const float* x  = (const float*)d_in[0];
    const float* w1 = (const float*)d_in[1];
    const float* w2 = (const float*)d_in[2];
    const float* ew = (const float*)d_in[3];
    const int*  row = (const int*)d_in[4];
    const int*  col = (const int*)d_in[5];
    float* out = (float*)d_out;

    char* ws = (char*)d_ws;
    int*    row_ptr = (int*)ws;
    int*    cursor  = (int*)(ws + 36864);
    ushort* zhi     = (ushort*)(ws + 73728);
    ushort* zlo     = (ushort*)(ws + 73728 + 262144);

    char* ob = (char*)d_out;
    ushort* support1 = (ushort*)ob;                       // 4MB bf16
    float*  s2       = (float*)(ob + 16u * 1024 * 1024);  // 512KB
    int*    col_s    = (int*)(ob + 17u * 1024 * 1024);    // 1MB
    float*  w_s      = (float*)(ob + 18u * 1024 * 1024);  // 1MB
    ushort* xbf      = (ushort*)(ob + 20u * 1024 * 1024); // 8MB
    ushort* w1tbf    = (ushort*)(ob + 36u * 1024 * 1024); // 256KB

    k_prep<<<4640, 256, 0, stream>>>(x, xbf, w1, w1tbf, cursor);

    k_hist<<<NE / 256, 256, 0, stream>>>(row, cursor);
    k_scan<<<1, 1024, 0, stream>>>(cursor, row_ptr, cursor);
    k_scatter<<<NE / 256, 256, 0, stream>>>(row, col, ew, cursor, col_s, w_s);

    k_gemm1_mfma<<<dim3(NN / 64, DH / 64), 256, 0, stream>>>(xbf, w1tbf, support1);
    k_spmm1_gemm2<<<NN / 2, 256, 0, stream>>>(support1, row_ptr, col_s, w_s, w2, s2);

    k_spmm2<<<NN / 16, 256, 0, stream>>>(s2, row_ptr, col_s, w_s, zhi, zlo);

    k_gemm3_mfma<<<dim3(NN / 128, NN / 128), 256, 0, stream>>>(zhi, zlo, out);
}